// Round 5
// baseline (240.364 us; speedup 1.0000x reference)
//
#include <hip/hip_runtime.h>
#include <hip/hip_bf16.h>
#include <math.h>

#define DTC 0.01f

typedef __attribute__((ext_vector_type(8))) short short8;   // 8 x bf16 (4 VGPRs)
typedef __attribute__((ext_vector_type(4))) float f32x4;    // MFMA C/D
typedef unsigned short bf16raw;

__device__ __forceinline__ bf16raw f2bf(float f){
  union { unsigned u; float f; } v; v.f = f;
  unsigned r = v.u + 0x7FFF + ((v.u >> 16) & 1u);   // round-to-nearest-even
  return (bf16raw)(r >> 16);
}

// Load 8 consecutive fp32, round to 8 bf16.
__device__ __forceinline__ short8 ld8f(const float* __restrict__ p){
  float4 a = *(const float4*)p;
  float4 b = *(const float4*)(p + 4);
  short8 r;
  r[0] = (short)f2bf(a.x); r[1] = (short)f2bf(a.y);
  r[2] = (short)f2bf(a.z); r[3] = (short)f2bf(a.w);
  r[4] = (short)f2bf(b.x); r[5] = (short)f2bf(b.y);
  r[6] = (short)f2bf(b.z); r[7] = (short)f2bf(b.w);
  return r;
}

// ---------------------------------------------------------------------------
// Async-stage ITERS*16 rows x 32 bf16 -> LDS [row][32], T2-swizzled.
// LDS dest linear (global_load_lds HW requirement); 16B k-slot permuted on
// the GLOBAL side (rule #21): slot (lane&3) holds k-chunk (lane&3)^((lane>>3)&3).
// Reader applies the same involution -> 2-way (free) bank access.
// ---------------------------------------------------------------------------
template<int ITERS>
__device__ __forceinline__ void stage_async(const bf16raw* __restrict__ src, long ld,
                                            long row0, int k0, bf16raw* lds,
                                            int wave, int lane){
  int kchunk = (lane & 3) ^ ((lane >> 3) & 3);
#pragma unroll
  for (int i = 0; i < ITERS; ++i){
    int r0 = (wave*ITERS + i) * 16;
    long row = row0 + r0 + (lane >> 2);
    const bf16raw* gp = src + row*ld + k0 + kchunk*8;
    bf16raw* lp = lds + r0*32;
    __builtin_amdgcn_global_load_lds((const __attribute__((address_space(1))) void*)gp,
                                     (__attribute__((address_space(3))) void*)lp,
                                     16, 0, 0);
  }
}

// One BK=32 step: MI A-frags + NI B-frags (ds_read_b128, swizzled slot) + MI*NI MFMA.
template<int MI, int NI>
__device__ __forceinline__ void mma_tile(const bf16raw* Alds, const bf16raw* Blds,
                                         f32x4 acc[MI][NI], int wm, int wn, int quad, int t16){
  short8 af[MI], bfr[NI];
  int sw = (quad ^ ((t16 >> 1) & 3)) * 8;   // physical 16B slot for this lane's rows
#pragma unroll
  for (int mi = 0; mi < MI; ++mi)
    af[mi] = *(const short8*)(Alds + (wm*(MI*16) + mi*16 + t16)*32 + sw);
#pragma unroll
  for (int ni = 0; ni < NI; ++ni)
    bfr[ni] = *(const short8*)(Blds + (wn*(NI*16) + ni*16 + t16)*32 + sw);
#pragma unroll
  for (int mi = 0; mi < MI; ++mi)
#pragma unroll
    for (int ni = 0; ni < NI; ++ni)
      acc[mi][ni] = __builtin_amdgcn_mfma_f32_16x16x32_bf16(af[mi], bfr[ni], acc[mi][ni], 0, 0, 0);
}

// ---------------------------------------------------------------------------
// Prep: fp32 -> bf16 for u, [W_omega|W_zeta|W_B] (concat), C, D_mat.
// ---------------------------------------------------------------------------
extern "C" __global__ void k_prep(const float* __restrict__ u,
    const float* __restrict__ Wom, const float* __restrict__ Wze,
    const float* __restrict__ WB, const float* __restrict__ Cm,
    const float* __restrict__ Dm, bf16raw* __restrict__ u_bf,
    bf16raw* __restrict__ Wcat, bf16raw* __restrict__ C_bf,
    bf16raw* __restrict__ Dm_bf){
  long g = (long)blockIdx.x * 256 + threadIdx.x;
  const float* src; bf16raw* dst; long o;
  if      (g < 2097152){ src = u;   dst = u_bf;          o = g; }
  else if (g < 2105344){ src = Wom; dst = Wcat;          o = g - 2097152; }
  else if (g < 2113536){ src = Wze; dst = Wcat + 65536;  o = g - 2105344; }
  else if (g < 2129920){ src = WB;  dst = Wcat + 131072; o = g - 2113536; }
  else if (g < 2146304){ src = Cm;  dst = C_bf;          o = g - 2129920; }
  else                 { src = Dm;  dst = Dm_bf;         o = g - 2146304; }
  *(short8*)(dst + o*8) = ld8f(src + o*8);
}

// ---------------------------------------------------------------------------
// K1: P[bt][n] = sum_d u[bt][d] * Wcat[n][d]  (16384 x 256, K=1024), fp32 out.
// Tile 64x64, 1024 blocks (4/CU, 16 waves/CU). 3-buffer single-barrier
// pipeline: vmcnt(2) -> s_barrier -> issue stage(s+2) -> MFMA(buf s%3).
// 2 loads/wave/stage; 2 stages in flight -> vmcnt(2).
// ---------------------------------------------------------------------------
extern "C" __global__ __launch_bounds__(256, 4) void k_gemm_p(
    const bf16raw* __restrict__ u_bf, const bf16raw* __restrict__ Wcat,
    float* __restrict__ P){
  __shared__ __align__(16) bf16raw Alds[3*64*32];    // 12 KB
  __shared__ __align__(16) bf16raw Blds[3*64*32];    // 12 KB
  int tid = threadIdx.x, wave = tid >> 6, lane = tid & 63;
  int quad = lane >> 4, t16 = lane & 15;
  int wm = wave >> 1, wn = wave & 1;                 // wave tile 32x32
  // XCD-aware swizzle: 1024 blocks, 8 XCDs x 128 consecutive sids each.
  int id  = blockIdx.y * gridDim.x + blockIdx.x;
  int sid = (id & 7) * 128 + (id >> 3);
  long row0 = (long)(sid >> 2) * 64;
  int  col0 = (sid & 3) * 64;
  f32x4 acc[2][2] = {};

  auto stage = [&](int kt, int buf){
    stage_async<1>(u_bf, 1024, row0, kt*32, Alds + buf*(64*32), wave, lane);
    stage_async<1>(Wcat, 1024, col0, kt*32, Blds + buf*(64*32), wave, lane);
  };

  stage(0, 0);
  stage(1, 1);
  int rd = 0;                                        // rd = s % 3
  for (int s = 0; s < 30; ++s){
    asm volatile("s_waitcnt vmcnt(2)" ::: "memory"); // own stage-s loads landed
    __builtin_amdgcn_s_barrier();                    // all waves' stage-s landed;
    __builtin_amdgcn_sched_barrier(0);               // buf (s-1)%3 fully consumed
    int st = rd >= 1 ? rd - 1 : 2;                   // (s+2)%3
    stage(s + 2, st);                                // issue early, before MFMA
    __builtin_amdgcn_s_setprio(1);
    mma_tile<2,2>(Alds + rd*(64*32), Blds + rd*(64*32), acc, wm, wn, quad, t16);
    __builtin_amdgcn_s_setprio(0);
    rd = rd < 2 ? rd + 1 : 0;
  }
  asm volatile("s_waitcnt vmcnt(2)" ::: "memory");   // s=30 reads buf 0
  __builtin_amdgcn_s_barrier();
  __builtin_amdgcn_sched_barrier(0);
  mma_tile<2,2>(Alds + 0*(64*32), Blds + 0*(64*32), acc, wm, wn, quad, t16);
  asm volatile("s_waitcnt vmcnt(0)" ::: "memory");   // s=31 reads buf 1
  __builtin_amdgcn_s_barrier();
  __builtin_amdgcn_sched_barrier(0);
  mma_tile<2,2>(Alds + 1*(64*32), Blds + 1*(64*32), acc, wm, wn, quad, t16);
#pragma unroll
  for (int mi = 0; mi < 2; ++mi)
#pragma unroll
    for (int ni = 0; ni < 2; ++ni)
#pragma unroll
      for (int r = 0; r < 4; ++r){
        long grow = row0 + wm*32 + mi*16 + quad*4 + r;
        int  gcol = col0 + wn*32 + ni*16 + t16;
        P[grow*256 + gcol] = acc[mi][ni][r];
      }
}

// ---------------------------------------------------------------------------
// K4: out[bt][d] = sum_n Xs[bt][n]*C[d][n] + sum_e u[bt][e]*Dm[d][e], fp32 out.
// Unified 36-step K-loop (4 steps Xs@C^T + 32 steps u@Dm^T).
// Tile 128x128, 1024 blocks, LDS 48 KB -> 3 blocks/CU (12 waves/CU).
// 3-buffer single-barrier pipeline; 4 loads/wave/stage -> vmcnt(4).
// XCD swizzle: all 8 col-tiles of a row-panel on one XCD (L2 reuse of u).
// ---------------------------------------------------------------------------
extern "C" __global__ __launch_bounds__(256, 3) void k_gemm_out(
    const bf16raw* __restrict__ Xs, const bf16raw* __restrict__ u_bf,
    const bf16raw* __restrict__ C_bf, const bf16raw* __restrict__ Dm_bf,
    float* __restrict__ out){
  __shared__ __align__(16) bf16raw Alds[3*128*32];   // 24 KB
  __shared__ __align__(16) bf16raw Blds[3*128*32];   // 24 KB
  int tid = threadIdx.x, wave = tid >> 6, lane = tid & 63;
  int quad = lane >> 4, t16 = lane & 15;
  int wm = wave >> 1, wn = wave & 1;                 // wave tile 64x64
  // XCD-aware swizzle: 1024 blocks, 8 XCDs x 128 consecutive sids each.
  int id  = blockIdx.y * gridDim.x + blockIdx.x;
  int sid = (id & 7) * 128 + (id >> 3);
  long row0 = (long)(sid >> 3) * 128;
  int  col0 = (sid & 7) * 128;
  f32x4 acc[4][4] = {};

  auto stage = [&](int s, int buf){
    if (s < 4){
      stage_async<2>(Xs,   128, row0, s*32, Alds + buf*(128*32), wave, lane);
      stage_async<2>(C_bf, 128, col0, s*32, Blds + buf*(128*32), wave, lane);
    } else {
      stage_async<2>(u_bf,  1024, row0, (s-4)*32, Alds + buf*(128*32), wave, lane);
      stage_async<2>(Dm_bf, 1024, col0, (s-4)*32, Blds + buf*(128*32), wave, lane);
    }
  };

  stage(0, 0);
  stage(1, 1);
  int rd = 0;                                        // rd = s % 3
  for (int s = 0; s < 34; ++s){
    asm volatile("s_waitcnt vmcnt(4)" ::: "memory"); // own stage-s loads landed
    __builtin_amdgcn_s_barrier();                    // all waves' stage-s landed;
    __builtin_amdgcn_sched_barrier(0);               // buf (s-1)%3 fully consumed
    int st = rd >= 1 ? rd - 1 : 2;                   // (s+2)%3
    stage(s + 2, st);                                // issue early, before MFMA
    __builtin_amdgcn_s_setprio(1);
    mma_tile<4,4>(Alds + rd*(128*32), Blds + rd*(128*32), acc, wm, wn, quad, t16);
    __builtin_amdgcn_s_setprio(0);
    rd = rd < 2 ? rd + 1 : 0;
  }
  asm volatile("s_waitcnt vmcnt(4)" ::: "memory");   // s=34 reads buf 1
  __builtin_amdgcn_s_barrier();
  __builtin_amdgcn_sched_barrier(0);
  mma_tile<4,4>(Alds + 1*(128*32), Blds + 1*(128*32), acc, wm, wn, quad, t16);
  asm volatile("s_waitcnt vmcnt(0)" ::: "memory");   // s=35 reads buf 2
  __builtin_amdgcn_s_barrier();
  __builtin_amdgcn_sched_barrier(0);
  mma_tile<4,4>(Alds + 2*(128*32), Blds + 2*(128*32), acc, wm, wn, quad, t16);
#pragma unroll
  for (int mi = 0; mi < 4; ++mi)
#pragma unroll
    for (int ni = 0; ni < 4; ++ni)
#pragma unroll
      for (int r = 0; r < 4; ++r){
        long grow = row0 + wm*64 + mi*16 + quad*4 + r;
        int  gcol = col0 + wn*64 + ni*16 + t16;
        out[grow*1024 + gcol] = acc[mi][ni][r];
      }
}

// ---------------------------------------------------------------------------
// scanA: coef + chunk summary. 256 chunks x 16 steps; block = chunk;
// thread tid = (b,m) series. Reads P, writes per-chunk 2x2 transition
// matrix CM and offset vector CV only (Coef buffer eliminated — scanC
// recomputes coefs from P, saving a 16 MB write + 16 MB read).
// ---------------------------------------------------------------------------
extern "C" __global__ __launch_bounds__(256) void k_scanA(
    const float* __restrict__ P, const float* __restrict__ b_om,
    const float* __restrict__ b_ze, const float* __restrict__ b_B,
    float4* __restrict__ CM, float2* __restrict__ CV){
  int tid = threadIdx.x, c = blockIdx.x;
  int b = tid >> 6, m = tid & 63;
  float bo = b_om[m], bz = b_ze[m], bb0 = b_B[m], bb1 = b_B[64 + m];
  const float* row = P + ((size_t)b*4096 + c*16) * 256;
  float m00=1.f, m01=0.f, m10=0.f, m11=0.f, vz=0.f, vy=0.f;
#pragma unroll 4
  for (int t = 0; t < 16; ++t){
    const float* r = row + t*256;
    float wo = r[m]       + bo;
    float wz = r[64 + m]  + bz;
    float fz = r[128 + m] + bb0;
    float fy = r[192 + m] + bb1;
    float sp = (wo > 20.f) ? wo : log1pf(expf(wo));
    float omega = fminf(fmaxf(sp, 1e-4f), 100.f);
    float A = omega * omega;
    float S = 1.f / (1.f + DTC*DTC*A);
    float zeta = 1.f / (1.f + expf(-wz));
    float p = (1.f - zeta) * S;
    float q = p * DTC * A;
    float nvz = p*vz - q*vy + fz;
    float nvy = DTC*p*vz + p*vy + fy;
    vz = nvz; vy = nvy;
    float n00 = p*m00 - q*m10;
    float n01 = p*m01 - q*m11;
    float n10 = DTC*p*m00 + p*m10;
    float n11 = DTC*p*m01 + p*m11;
    m00=n00; m01=n01; m10=n10; m11=n11;
  }
  CM[c*256 + tid] = make_float4(m00, m01, m10, m11);
  CV[c*256 + tid] = make_float2(vz, vy);
}

// ---------------------------------------------------------------------------
// scanC: block c composes its own exclusive chunk prefix from CM/CV
// (parallel across blocks), then recomputes coefs from P (bit-identical to
// scanA's) and applies its chunk, writing Xs (bf16). Xs no longer overlays
// P (scanC reads P) — it lives in its own region.
// ---------------------------------------------------------------------------
extern "C" __global__ __launch_bounds__(256) void k_scanC(
    const float* __restrict__ P, const float* __restrict__ b_om,
    const float* __restrict__ b_ze, const float* __restrict__ b_B,
    const float4* __restrict__ CM, const float2* __restrict__ CV,
    bf16raw* __restrict__ Xs){
  int tid = threadIdx.x, c = blockIdx.x;
  int b = tid >> 6, m = tid & 63;
  float xz = 0.f, xy = 0.f;
#pragma unroll 4
  for (int j = 0; j < c; ++j){
    float4 Mv = CM[j*256 + tid];
    float2 Vv = CV[j*256 + tid];
    float nz = Mv.x*xz + Mv.y*xy + Vv.x;
    float ny = Mv.z*xz + Mv.w*xy + Vv.y;
    xz = nz; xy = ny;
  }
  float bo = b_om[m], bz = b_ze[m], bb0 = b_B[m], bb1 = b_B[64 + m];
  const float* row = P + ((size_t)b*4096 + c*16) * 256;
  bf16raw* xp = Xs + ((size_t)b*4096 + c*16) * 128 + m;
#pragma unroll 4
  for (int t = 0; t < 16; ++t){
    const float* r = row + t*256;
    float wo = r[m]       + bo;
    float wz = r[64 + m]  + bz;
    float fz = r[128 + m] + bb0;
    float fy = r[192 + m] + bb1;
    float sp = (wo > 20.f) ? wo : log1pf(expf(wo));
    float omega = fminf(fmaxf(sp, 1e-4f), 100.f);
    float A = omega * omega;
    float S = 1.f / (1.f + DTC*DTC*A);
    float zeta = 1.f / (1.f + expf(-wz));
    float p = (1.f - zeta) * S;
    float q = p * DTC * A;
    float nz = p*xz - q*xy + fz;
    float ny = DTC*p*xz + p*xy + fy;
    xz = nz; xy = ny;
    xp[t*128]      = f2bf(xz);   // z part: n = m
    xp[t*128 + 64] = f2bf(xy);   // y part: n = 64 + m
  }
}

// ---------------------------------------------------------------------------
extern "C" void kernel_launch(void* const* d_in, const int* in_sizes, int n_in,
                              void* d_out, int out_size, void* d_ws, size_t ws_size,
                              hipStream_t stream){
  const float* u   = (const float*)d_in[0];
  const float* Wom = (const float*)d_in[1];
  const float* bom = (const float*)d_in[2];
  const float* Wze = (const float*)d_in[3];
  const float* bze = (const float*)d_in[4];
  const float* WB  = (const float*)d_in[5];
  const float* bB  = (const float*)d_in[6];
  const float* Cm  = (const float*)d_in[7];
  const float* Dm  = (const float*)d_in[8];
  float* out = (float*)d_out;

  char* ws = (char*)d_ws;
  size_t off = 0;
  bf16raw* u_bf  = (bf16raw*)(ws + off); off += (size_t)16777216*2;    // 32 MB
  bf16raw* Wcat  = (bf16raw*)(ws + off); off += (size_t)262144*2;      // 512 KB
  bf16raw* C_bf  = (bf16raw*)(ws + off); off += (size_t)131072*2;      // 256 KB
  bf16raw* Dm_bf = (bf16raw*)(ws + off); off += (size_t)1048576*2;     // 2 MB
  float*   P     = (float*)  (ws + off); off += (size_t)16384*256*4;   // 16 MB
  bf16raw* Xs    = (bf16raw*)(ws + off); off += (size_t)16384*128*2;   // 4 MB
  float4*  CMw   = (float4*) (ws + off); off += (size_t)256*256*16;    // 1 MB
  float2*  CVw   = (float2*) (ws + off); off += (size_t)256*256*8;     // 512 KB

  k_prep    <<<8896, 256, 0, stream>>>(u, Wom, Wze, WB, Cm, Dm, u_bf, Wcat, C_bf, Dm_bf);
  k_gemm_p  <<<dim3(4, 256), 256, 0, stream>>>(u_bf, Wcat, P);
  k_scanA   <<<256, 256, 0, stream>>>(P, bom, bze, bB, CMw, CVw);
  k_scanC   <<<256, 256, 0, stream>>>(P, bom, bze, bB, CMw, CVw, Xs);
  k_gemm_out<<<dim3(8, 128), 256, 0, stream>>>(Xs, u_bf, C_bf, Dm_bf, out);
}

// Round 6
// 214.292 us; speedup vs baseline: 1.1217x; 1.1217x over previous
//
#include <hip/hip_runtime.h>
#include <hip/hip_bf16.h>
#include <math.h>

#define DTC 0.01f

typedef __attribute__((ext_vector_type(8))) short short8;   // 8 x bf16 (4 VGPRs)
typedef __attribute__((ext_vector_type(4))) float f32x4;    // MFMA C/D
typedef unsigned short bf16raw;

__device__ __forceinline__ bf16raw f2bf(float f){
  union { unsigned u; float f; } v; v.f = f;
  unsigned r = v.u + 0x7FFF + ((v.u >> 16) & 1u);   // round-to-nearest-even
  return (bf16raw)(r >> 16);
}

// Load 8 consecutive fp32, round to 8 bf16.
__device__ __forceinline__ short8 ld8f(const float* __restrict__ p){
  float4 a = *(const float4*)p;
  float4 b = *(const float4*)(p + 4);
  short8 r;
  r[0] = (short)f2bf(a.x); r[1] = (short)f2bf(a.y);
  r[2] = (short)f2bf(a.z); r[3] = (short)f2bf(a.w);
  r[4] = (short)f2bf(b.x); r[5] = (short)f2bf(b.y);
  r[6] = (short)f2bf(b.z); r[7] = (short)f2bf(b.w);
  return r;
}

// ---------------------------------------------------------------------------
// Async-stage ITERS*16 rows x 32 bf16 -> LDS [row][32], T2-swizzled.
// LDS dest linear (global_load_lds HW requirement); 16B k-slot permuted on
// the GLOBAL side (rule #21): slot (lane&3) holds k-chunk (lane&3)^((lane>>3)&3).
// Reader applies the same involution -> 2-way (free) bank access.
// ---------------------------------------------------------------------------
template<int ITERS>
__device__ __forceinline__ void stage_async(const bf16raw* __restrict__ src, long ld,
                                            long row0, int k0, bf16raw* lds,
                                            int wave, int lane){
  int kchunk = (lane & 3) ^ ((lane >> 3) & 3);
#pragma unroll
  for (int i = 0; i < ITERS; ++i){
    int r0 = (wave*ITERS + i) * 16;
    long row = row0 + r0 + (lane >> 2);
    const bf16raw* gp = src + row*ld + k0 + kchunk*8;
    bf16raw* lp = lds + r0*32;
    __builtin_amdgcn_global_load_lds((const __attribute__((address_space(1))) void*)gp,
                                     (__attribute__((address_space(3))) void*)lp,
                                     16, 0, 0);
  }
}

// One BK=32 step: MI A-frags + NI B-frags (ds_read_b128, swizzled slot) + MI*NI MFMA.
template<int MI, int NI>
__device__ __forceinline__ void mma_tile(const bf16raw* Alds, const bf16raw* Blds,
                                         f32x4 acc[MI][NI], int wm, int wn, int quad, int t16){
  short8 af[MI], bfr[NI];
  int sw = (quad ^ ((t16 >> 1) & 3)) * 8;   // physical 16B slot for this lane's rows
#pragma unroll
  for (int mi = 0; mi < MI; ++mi)
    af[mi] = *(const short8*)(Alds + (wm*(MI*16) + mi*16 + t16)*32 + sw);
#pragma unroll
  for (int ni = 0; ni < NI; ++ni)
    bfr[ni] = *(const short8*)(Blds + (wn*(NI*16) + ni*16 + t16)*32 + sw);
#pragma unroll
  for (int mi = 0; mi < MI; ++mi)
#pragma unroll
    for (int ni = 0; ni < NI; ++ni)
      acc[mi][ni] = __builtin_amdgcn_mfma_f32_16x16x32_bf16(af[mi], bfr[ni], acc[mi][ni], 0, 0, 0);
}

// ---------------------------------------------------------------------------
// Prep: fp32 -> bf16 for u, [W_omega|W_zeta|W_B] (concat), C, D_mat.
// ---------------------------------------------------------------------------
extern "C" __global__ void k_prep(const float* __restrict__ u,
    const float* __restrict__ Wom, const float* __restrict__ Wze,
    const float* __restrict__ WB, const float* __restrict__ Cm,
    const float* __restrict__ Dm, bf16raw* __restrict__ u_bf,
    bf16raw* __restrict__ Wcat, bf16raw* __restrict__ C_bf,
    bf16raw* __restrict__ Dm_bf){
  long g = (long)blockIdx.x * 256 + threadIdx.x;
  const float* src; bf16raw* dst; long o;
  if      (g < 2097152){ src = u;   dst = u_bf;          o = g; }
  else if (g < 2105344){ src = Wom; dst = Wcat;          o = g - 2097152; }
  else if (g < 2113536){ src = Wze; dst = Wcat + 65536;  o = g - 2105344; }
  else if (g < 2129920){ src = WB;  dst = Wcat + 131072; o = g - 2113536; }
  else if (g < 2146304){ src = Cm;  dst = C_bf;          o = g - 2129920; }
  else                 { src = Dm;  dst = Dm_bf;         o = g - 2146304; }
  *(short8*)(dst + o*8) = ld8f(src + o*8);
}

// ---------------------------------------------------------------------------
// K1: P[bt][n] = sum_d u[bt][d] * Wcat[n][d]  (16384 x 256, K=1024), fp32 out.
// Tile 64x64, 1024 blocks (4/CU). 3-buffer single-barrier pipeline:
// vmcnt(2) -> s_barrier -> issue stage(s+2) -> MFMA(buf s%3).
// ---------------------------------------------------------------------------
extern "C" __global__ __launch_bounds__(256, 4) void k_gemm_p(
    const bf16raw* __restrict__ u_bf, const bf16raw* __restrict__ Wcat,
    float* __restrict__ P){
  __shared__ __align__(16) bf16raw Alds[3*64*32];    // 12 KB
  __shared__ __align__(16) bf16raw Blds[3*64*32];    // 12 KB
  int tid = threadIdx.x, wave = tid >> 6, lane = tid & 63;
  int quad = lane >> 4, t16 = lane & 15;
  int wm = wave >> 1, wn = wave & 1;                 // wave tile 32x32
  // XCD-aware swizzle: 1024 blocks, 8 XCDs x 128 consecutive sids each.
  int id  = blockIdx.y * gridDim.x + blockIdx.x;
  int sid = (id & 7) * 128 + (id >> 3);
  long row0 = (long)(sid >> 2) * 64;
  int  col0 = (sid & 3) * 64;
  f32x4 acc[2][2] = {};

  auto stage = [&](int kt, int buf){
    stage_async<1>(u_bf, 1024, row0, kt*32, Alds + buf*(64*32), wave, lane);
    stage_async<1>(Wcat, 1024, col0, kt*32, Blds + buf*(64*32), wave, lane);
  };

  stage(0, 0);
  stage(1, 1);
  int rd = 0;                                        // rd = s % 3
  for (int s = 0; s < 30; ++s){
    asm volatile("s_waitcnt vmcnt(2)" ::: "memory"); // own stage-s loads landed
    __builtin_amdgcn_s_barrier();                    // all waves' stage-s landed;
    __builtin_amdgcn_sched_barrier(0);               // buf (s-1)%3 fully consumed
    int st = rd >= 1 ? rd - 1 : 2;                   // (s+2)%3
    stage(s + 2, st);                                // issue early, before MFMA
    __builtin_amdgcn_s_setprio(1);
    mma_tile<2,2>(Alds + rd*(64*32), Blds + rd*(64*32), acc, wm, wn, quad, t16);
    __builtin_amdgcn_s_setprio(0);
    rd = rd < 2 ? rd + 1 : 0;
  }
  asm volatile("s_waitcnt vmcnt(2)" ::: "memory");   // s=30 reads buf 0
  __builtin_amdgcn_s_barrier();
  __builtin_amdgcn_sched_barrier(0);
  mma_tile<2,2>(Alds + 0*(64*32), Blds + 0*(64*32), acc, wm, wn, quad, t16);
  asm volatile("s_waitcnt vmcnt(0)" ::: "memory");   // s=31 reads buf 1
  __builtin_amdgcn_s_barrier();
  __builtin_amdgcn_sched_barrier(0);
  mma_tile<2,2>(Alds + 1*(64*32), Blds + 1*(64*32), acc, wm, wn, quad, t16);
#pragma unroll
  for (int mi = 0; mi < 2; ++mi)
#pragma unroll
    for (int ni = 0; ni < 2; ++ni)
#pragma unroll
      for (int r = 0; r < 4; ++r){
        long grow = row0 + wm*32 + mi*16 + quad*4 + r;
        int  gcol = col0 + wn*32 + ni*16 + t16;
        P[grow*256 + gcol] = acc[mi][ni][r];
      }
}

// ---------------------------------------------------------------------------
// K4: out[bt][d] = sum_n Xs[bt][n]*C[d][n] + sum_e u[bt][e]*Dm[d][e], fp32 out.
// REVERTED to round-4 config (measured 52.2 us): tile 128x256, grid 512,
// 3-buffer single-barrier pipeline, vmcnt(6), LDS 72 KB -> 2 blocks/CU.
// ---------------------------------------------------------------------------
extern "C" __global__ __launch_bounds__(256, 2) void k_gemm_out(
    const bf16raw* __restrict__ Xs, const bf16raw* __restrict__ u_bf,
    const bf16raw* __restrict__ C_bf, const bf16raw* __restrict__ Dm_bf,
    float* __restrict__ out){
  __shared__ __align__(16) bf16raw Alds[3*128*32];   // 24 KB
  __shared__ __align__(16) bf16raw Blds[3*256*32];   // 48 KB
  int tid = threadIdx.x, wave = tid >> 6, lane = tid & 63;
  int quad = lane >> 4, t16 = lane & 15;
  int wm = wave >> 1, wn = wave & 1;                 // wave tile 64x128
  // XCD-aware swizzle: 512 blocks, 8 XCDs x 64 consecutive blocks each.
  int id  = blockIdx.y * gridDim.x + blockIdx.x;
  int sid = (id & 7) * 64 + (id >> 3);
  long row0 = (long)(sid >> 2) * 128;
  int  col0 = (sid & 3) * 256;
  f32x4 acc[4][8] = {};

  auto stage = [&](int s, int buf){
    if (s < 4){
      stage_async<2>(Xs,   128, row0, s*32, Alds + buf*(128*32), wave, lane);
      stage_async<4>(C_bf, 128, col0, s*32, Blds + buf*(256*32), wave, lane);
    } else {
      stage_async<2>(u_bf,  1024, row0, (s-4)*32, Alds + buf*(128*32), wave, lane);
      stage_async<4>(Dm_bf, 1024, col0, (s-4)*32, Blds + buf*(256*32), wave, lane);
    }
  };

  stage(0, 0);
  stage(1, 1);
  int rd = 0;                                        // rd = s % 3
  for (int s = 0; s < 34; ++s){
    asm volatile("s_waitcnt vmcnt(6)" ::: "memory"); // own stage-s loads landed
    __builtin_amdgcn_s_barrier();                    // all waves' stage-s landed;
    __builtin_amdgcn_sched_barrier(0);               // buf (s-1)%3 fully consumed
    int st = rd >= 1 ? rd - 1 : 2;                   // (s+2)%3
    stage(s + 2, st);                                // issue early, before MFMA
    __builtin_amdgcn_s_setprio(1);
    mma_tile<4,8>(Alds + rd*(128*32), Blds + rd*(256*32), acc, wm, wn, quad, t16);
    __builtin_amdgcn_s_setprio(0);
    rd = rd < 2 ? rd + 1 : 0;
  }
  asm volatile("s_waitcnt vmcnt(6)" ::: "memory");   // s=34 reads buf 1
  __builtin_amdgcn_s_barrier();
  __builtin_amdgcn_sched_barrier(0);
  mma_tile<4,8>(Alds + 1*(128*32), Blds + 1*(256*32), acc, wm, wn, quad, t16);
  asm volatile("s_waitcnt vmcnt(0)" ::: "memory");   // s=35 reads buf 2
  __builtin_amdgcn_s_barrier();
  __builtin_amdgcn_sched_barrier(0);
  mma_tile<4,8>(Alds + 2*(128*32), Blds + 2*(256*32), acc, wm, wn, quad, t16);
#pragma unroll
  for (int mi = 0; mi < 4; ++mi)
#pragma unroll
    for (int ni = 0; ni < 8; ++ni)
#pragma unroll
      for (int r = 0; r < 4; ++r){
        long grow = row0 + wm*64 + mi*16 + quad*4 + r;
        int  gcol = col0 + wn*128 + ni*16 + t16;
        out[grow*1024 + gcol] = acc[mi][ni][r];
      }
}

// ---------------------------------------------------------------------------
// scanA: coef + chunk summary. 256 chunks x 16 steps; block = chunk;
// thread tid = (b,m) series. Reads P, writes per-chunk 2x2 transition
// matrix CM and offset vector CV (coefs recomputed downstream from P).
// ---------------------------------------------------------------------------
extern "C" __global__ __launch_bounds__(256) void k_scanA(
    const float* __restrict__ P, const float* __restrict__ b_om,
    const float* __restrict__ b_ze, const float* __restrict__ b_B,
    float4* __restrict__ CM, float2* __restrict__ CV){
  int tid = threadIdx.x, c = blockIdx.x;
  int b = tid >> 6, m = tid & 63;
  float bo = b_om[m], bz = b_ze[m], bb0 = b_B[m], bb1 = b_B[64 + m];
  const float* row = P + ((size_t)b*4096 + c*16) * 256;
  float m00=1.f, m01=0.f, m10=0.f, m11=0.f, vz=0.f, vy=0.f;
#pragma unroll 4
  for (int t = 0; t < 16; ++t){
    const float* r = row + t*256;
    float wo = r[m]       + bo;
    float wz = r[64 + m]  + bz;
    float fz = r[128 + m] + bb0;
    float fy = r[192 + m] + bb1;
    float sp = (wo > 20.f) ? wo : log1pf(expf(wo));
    float omega = fminf(fmaxf(sp, 1e-4f), 100.f);
    float A = omega * omega;
    float S = 1.f / (1.f + DTC*DTC*A);
    float zeta = 1.f / (1.f + expf(-wz));
    float p = (1.f - zeta) * S;
    float q = p * DTC * A;
    float nvz = p*vz - q*vy + fz;
    float nvy = DTC*p*vz + p*vy + fy;
    vz = nvz; vy = nvy;
    float n00 = p*m00 - q*m10;
    float n01 = p*m01 - q*m11;
    float n10 = DTC*p*m00 + p*m10;
    float n11 = DTC*p*m01 + p*m11;
    m00=n00; m01=n01; m10=n10; m11=n11;
  }
  CM[c*256 + tid] = make_float4(m00, m01, m10, m11);
  CV[c*256 + tid] = make_float2(vz, vy);
}

// ---------------------------------------------------------------------------
// scanB: Kogge-Stone scan over the 256 chunk summaries, one block per
// series (blockIdx = series s, threadIdx = chunk c). 8 LDS rounds compose
// (M,V) pairs; XIn[c] = V of inclusive[c-1] (x0 = 0). Replaces scanC's
// O(c) per-block prefix loop (block 255 streamed 1.5 MB serially).
// Compose later∘earlier: M = Ml*Me, V = Ml*Ve + Vl.
// ---------------------------------------------------------------------------
extern "C" __global__ __launch_bounds__(256) void k_scanB(
    const float4* __restrict__ CM, const float2* __restrict__ CV,
    float2* __restrict__ XIn){
  __shared__ float sm[6][256];
  int s = blockIdx.x;            // series (b*64+m)
  int c = threadIdx.x;           // chunk
  float4 Mv = CM[(size_t)c*256 + s];
  float2 Vv = CV[(size_t)c*256 + s];
  float m00=Mv.x, m01=Mv.y, m10=Mv.z, m11=Mv.w, vz=Vv.x, vy=Vv.y;
#pragma unroll
  for (int off = 1; off < 256; off <<= 1){
    sm[0][c]=m00; sm[1][c]=m01; sm[2][c]=m10; sm[3][c]=m11; sm[4][c]=vz; sm[5][c]=vy;
    __syncthreads();
    if (c >= off){
      int p = c - off;
      float e00=sm[0][p], e01=sm[1][p], e10=sm[2][p], e11=sm[3][p];
      float evz=sm[4][p], evy=sm[5][p];
      float n00 = m00*e00 + m01*e10;
      float n01 = m00*e01 + m01*e11;
      float n10 = m10*e00 + m11*e10;
      float n11 = m10*e01 + m11*e11;
      float nvz = m00*evz + m01*evy + vz;
      float nvy = m10*evz + m11*evy + vy;
      m00=n00; m01=n01; m10=n10; m11=n11; vz=nvz; vy=nvy;
    }
    __syncthreads();
  }
  // thread c holds inclusive composition of chunks [0..c]; x0 = 0 so the
  // state entering chunk c+1 is just V.
  if (c < 255) XIn[(size_t)(c+1)*256 + s] = make_float2(vz, vy);
  if (c == 0)  XIn[s] = make_float2(0.f, 0.f);
}

// ---------------------------------------------------------------------------
// scanC: pure streaming now — read chunk-start state from XIn, recompute
// coefs from P (bit-identical to scanA's), apply chunk, write Xs (bf16).
// ---------------------------------------------------------------------------
extern "C" __global__ __launch_bounds__(256) void k_scanC(
    const float* __restrict__ P, const float* __restrict__ b_om,
    const float* __restrict__ b_ze, const float* __restrict__ b_B,
    const float2* __restrict__ XIn, bf16raw* __restrict__ Xs){
  int tid = threadIdx.x, c = blockIdx.x;
  int b = tid >> 6, m = tid & 63;
  float2 x0 = XIn[(size_t)c*256 + tid];
  float xz = x0.x, xy = x0.y;
  float bo = b_om[m], bz = b_ze[m], bb0 = b_B[m], bb1 = b_B[64 + m];
  const float* row = P + ((size_t)b*4096 + c*16) * 256;
  bf16raw* xp = Xs + ((size_t)b*4096 + c*16) * 128 + m;
#pragma unroll 4
  for (int t = 0; t < 16; ++t){
    const float* r = row + t*256;
    float wo = r[m]       + bo;
    float wz = r[64 + m]  + bz;
    float fz = r[128 + m] + bb0;
    float fy = r[192 + m] + bb1;
    float sp = (wo > 20.f) ? wo : log1pf(expf(wo));
    float omega = fminf(fmaxf(sp, 1e-4f), 100.f);
    float A = omega * omega;
    float S = 1.f / (1.f + DTC*DTC*A);
    float zeta = 1.f / (1.f + expf(-wz));
    float p = (1.f - zeta) * S;
    float q = p * DTC * A;
    float nz = p*xz - q*xy + fz;
    float ny = DTC*p*xz + p*xy + fy;
    xz = nz; xy = ny;
    xp[t*128]      = f2bf(xz);   // z part: n = m
    xp[t*128 + 64] = f2bf(xy);   // y part: n = 64 + m
  }
}

// ---------------------------------------------------------------------------
extern "C" void kernel_launch(void* const* d_in, const int* in_sizes, int n_in,
                              void* d_out, int out_size, void* d_ws, size_t ws_size,
                              hipStream_t stream){
  const float* u   = (const float*)d_in[0];
  const float* Wom = (const float*)d_in[1];
  const float* bom = (const float*)d_in[2];
  const float* Wze = (const float*)d_in[3];
  const float* bze = (const float*)d_in[4];
  const float* WB  = (const float*)d_in[5];
  const float* bB  = (const float*)d_in[6];
  const float* Cm  = (const float*)d_in[7];
  const float* Dm  = (const float*)d_in[8];
  float* out = (float*)d_out;

  char* ws = (char*)d_ws;
  size_t off = 0;
  bf16raw* u_bf  = (bf16raw*)(ws + off); off += (size_t)16777216*2;    // 32 MB
  bf16raw* Wcat  = (bf16raw*)(ws + off); off += (size_t)262144*2;      // 512 KB
  bf16raw* C_bf  = (bf16raw*)(ws + off); off += (size_t)131072*2;      // 256 KB
  bf16raw* Dm_bf = (bf16raw*)(ws + off); off += (size_t)1048576*2;     // 2 MB
  float*   P     = (float*)  (ws + off); off += (size_t)16384*256*4;   // 16 MB
  bf16raw* Xs    = (bf16raw*)(ws + off); off += (size_t)16384*128*2;   // 4 MB
  float4*  CMw   = (float4*) (ws + off); off += (size_t)256*256*16;    // 1 MB
  float2*  CVw   = (float2*) (ws + off); off += (size_t)256*256*8;     // 512 KB
  float2*  XIn   = (float2*) (ws + off); off += (size_t)256*256*8;     // 512 KB

  k_prep    <<<8896, 256, 0, stream>>>(u, Wom, Wze, WB, Cm, Dm, u_bf, Wcat, C_bf, Dm_bf);
  k_gemm_p  <<<dim3(4, 256), 256, 0, stream>>>(u_bf, Wcat, P);
  k_scanA   <<<256, 256, 0, stream>>>(P, bom, bze, bB, CMw, CVw);
  k_scanB   <<<256, 256, 0, stream>>>(CMw, CVw, XIn);
  k_scanC   <<<256, 256, 0, stream>>>(P, bom, bze, bB, XIn, Xs);
  k_gemm_out<<<dim3(4, 128), 256, 0, stream>>>(Xs, u_bf, C_bf, Dm_bf, out);
}